// Round 20
// baseline (5510.970 us; speedup 1.0000x reference)
//
#include <hip/hip_runtime.h>
#include <hip/hip_bf16.h>

#define Bq 64
#define Tq 512
#define Eq 128
#define Hq 256
#define NTAGS 50
#define Mq (Bq*Tq)   // 32768

typedef _Float16 v8hf __attribute__((ext_vector_type(8)));
typedef _Float16 v4hf __attribute__((ext_vector_type(4)));
typedef float v4f __attribute__((ext_vector_type(4)));

__device__ __forceinline__ float sigmoidf_(float x) { return 1.f / (1.f + __expf(-x)); }
__device__ __forceinline__ float tanhf_(float x) {
    float e = __expf(2.f * x);
    return 1.f - 2.f / (e + 1.f);
}

// ---------------- dtype detection: int32 vs int64 for words/lengths ----------------
__global__ void detect_int64(const unsigned* __restrict__ words,
                             const unsigned* __restrict__ lens,
                             unsigned* __restrict__ dflags) {
    __shared__ int wbad, lbad, wnz, lnz;
    if (threadIdx.x == 0) { wbad = 0; lbad = 0; wnz = 0; lnz = 0; }
    __syncthreads();
    for (int i = threadIdx.x; i < 16384; i += blockDim.x) {
        if (words[2 * i + 1] != 0u) wbad = 1;
        if (words[2 * i] != 0u) wnz = 1;
    }
    for (int i = threadIdx.x; i < 32; i += blockDim.x) {
        if (lens[2 * i + 1] != 0u) lbad = 1;
        if (lens[2 * i] != 0u) lnz = 1;
    }
    __syncthreads();
    if (threadIdx.x == 0) {
        unsigned f = 0;
        if (!wbad && wnz) f |= 1u;
        if (!lbad && lnz) f |= 2u;
        dflags[0] = f;
    }
}

// ---------------- bias: bias[l][d][n] = bih + bhh ----------------
__global__ void bias_kernel(const float* b1f_ih, const float* b1f_hh,
                            const float* b1b_ih, const float* b1b_hh,
                            const float* b2f_ih, const float* b2f_hh,
                            const float* b2b_ih, const float* b2b_hh,
                            float* bias) {   // [4][1024]: l1f,l1b,l2f,l2b
    int i = blockIdx.x * blockDim.x + threadIdx.x;
    if (i >= 4096) return;
    int l = i >> 11, d = (i >> 10) & 1, nn = i & 1023;
    float v;
    if (l == 0) v = d ? (b1b_ih[nn] + b1b_hh[nn]) : (b1f_ih[nn] + b1f_hh[nn]);
    else        v = d ? (b2b_ih[nn] + b2b_hh[nn]) : (b2f_ih[nn] + b2f_hh[nn]);
    bias[i] = v;
}

// ---------------- Whh -> MFMA A-fragment packing (gate-interleaved M-tiles) ----------------
// frag fg = w*32 + g*8 + kc  (w=wave 0..15, g=gate 0..3, kc=K-chunk 0..7)
// lane holds A[grow = g*256 + w*16 + (lane&15)][k = kc*32 + (lane>>4)*8 + i]
// -> wave w's 4 accumulators hold all 4 gates of units j in [w*16, w*16+16).
__global__ void pack_whh_mfma(const float* __restrict__ W, _Float16* __restrict__ PA) {
    int t = blockIdx.x * 256 + threadIdx.x;   // chunk id 0..32767
    if (t >= 32768) return;
    int fg = t >> 6, lane = t & 63;
    int w = fg >> 5, rem = fg & 31, g = rem >> 3, kc = rem & 7;
    int grow = g * 256 + w * 16 + (lane & 15);
    int kb = kc * 32 + (lane >> 4) * 8;
    _Float16 h8[8];
    #pragma unroll
    for (int i = 0; i < 8; ++i) h8[i] = (_Float16)W[(size_t)grow * 256 + kb + i];
    *(uint4*)(PA + ((size_t)fg * 64 + lane) * 8) = *(const uint4*)h8;
}

// ---------------- generic W[N][K] f32 -> MFMA B-fragment packing (verified r19) ----------------
__global__ void pack_w_bfrag(const float* __restrict__ W, _Float16* __restrict__ PB,
                             int Nvalid, int K, int nchunks) {
    int t = blockIdx.x * 256 + threadIdx.x;
    if (t >= nchunks) return;
    int fg = t >> 6, lane = t & 63;
    int kcn = K >> 5;
    int ntile = fg / kcn, kc = fg % kcn;
    int n = ntile * 16 + (lane & 15);
    int kb = kc * 32 + (lane >> 4) * 8;
    _Float16 h8[8];
    #pragma unroll
    for (int i = 0; i < 8; ++i)
        h8[i] = (n < Nvalid) ? (_Float16)W[(size_t)n * K + kb + i] : (_Float16)0.f;
    *(uint4*)(PB + ((size_t)fg * 64 + lane) * 8) = *(const uint4*)h8;
}

// ---------------- MFMA GEMM (verified round 19, unchanged) ----------------
template<int AMODE, int OUTT>
__global__ __launch_bounds__(256)
void gemm_mfma(const _Float16* __restrict__ Asrc, const unsigned* __restrict__ words_u32,
               const float* __restrict__ emb, const unsigned* __restrict__ dflags,
               const _Float16* __restrict__ PB, const float* __restrict__ bias,
               void* __restrict__ Cptr, int Nstr, int K, int Nvalid)
{
    __shared__ _Float16 At[64 * 40];
    const int tid = threadIdx.x;
    const int w = tid >> 6, lane = tid & 63;
    const int n0w = blockIdx.x * 256 + w * 64;
    const int m0 = blockIdx.y * 64;
    const int srow = tid >> 2, sseg = tid & 3;
    const int kcn = K >> 5;
    const int ntb = n0w >> 4;
    bool w64 = false;
    if (AMODE == 2) w64 = (dflags[0] & 1u) != 0u;

    v4f acc[4][4] = {};
    for (int kc0 = 0; kc0 < kcn; ++kc0) {
        if (AMODE == 0) {
            uint4 v = *(const uint4*)(Asrc + (size_t)(m0 + srow) * K + kc0 * 32 + sseg * 8);
            *(uint4*)(At + srow * 40 + sseg * 8) = v;
        } else {
            int wd = (int)(w64 ? words_u32[2 * (m0 + srow)] : words_u32[m0 + srow]);
            const float* src = emb + (size_t)wd * Eq + kc0 * 32 + sseg * 8;
            float4 v0 = *(const float4*)src;
            float4 v1 = *(const float4*)(src + 4);
            _Float16 h8[8] = {(_Float16)v0.x, (_Float16)v0.y, (_Float16)v0.z, (_Float16)v0.w,
                              (_Float16)v1.x, (_Float16)v1.y, (_Float16)v1.z, (_Float16)v1.w};
            *(uint4*)(At + srow * 40 + sseg * 8) = *(const uint4*)h8;
        }
        __syncthreads();
        v8hf Bf[4];
        #pragma unroll
        for (int nf = 0; nf < 4; ++nf) {
            size_t fg = (size_t)(ntb + nf) * kcn + kc0;
            Bf[nf] = __builtin_bit_cast(v8hf, *(const uint4*)(PB + (fg * 64 + lane) * 8));
        }
        #pragma unroll
        for (int mf = 0; mf < 4; ++mf) {
            v8hf Af = __builtin_bit_cast(v8hf,
                *(const uint4*)(At + (mf * 16 + (lane & 15)) * 40 + (lane >> 4) * 8));
            #pragma unroll
            for (int nf = 0; nf < 4; ++nf)
                acc[mf][nf] = __builtin_amdgcn_mfma_f32_16x16x32_f16(Af, Bf[nf], acc[mf][nf], 0, 0, 0);
        }
        __syncthreads();
    }
    #pragma unroll
    for (int nf = 0; nf < 4; ++nf) {
        int colb = n0w + nf * 16 + (lane & 15);
        float bb = (colb < Nvalid) ? bias[colb] : 0.f;
        #pragma unroll
        for (int mf = 0; mf < 4; ++mf) {
            int rowb = m0 + mf * 16 + (lane >> 4) * 4;
            #pragma unroll
            for (int r = 0; r < 4; ++r) {
                float v = acc[mf][nf][r] + bb;
                if (OUTT == 1) {
                    ((_Float16*)Cptr)[(size_t)(rowb + r) * Nstr + colb] = (_Float16)v;
                } else {
                    if (colb < Nvalid)
                        ((float*)Cptr)[(size_t)(rowb + r) * Nstr + colb] = v;
                }
            }
        }
    }
}

// ---------------- MFMA LSTM, in-lane update (gate-interleaved tiles) ----------------
// 32 blocks x 1024 threads (16 waves). Wave w: units j in [w*16, w*16+16);
// acc_g = gate g. Lane (n<4, kg): all 4 gates of units j = w*16+kg*4+{0..3},
// batch b0+n; LSTM update fully in-lane (c,h in regs). ONE barrier per step.
// W residency: regs g0/kc0-3, LDS g1/kc0-7 + g2/kc0, stream 19 frags (304 KB/step).
__global__ __launch_bounds__(1024)
void lstm_mfma(const _Float16* __restrict__ xg,   // [M][2048] f16, col = dir*1024+g*256+j
               const _Float16* __restrict__ PAf, const _Float16* __restrict__ PAb,
               const unsigned* __restrict__ len_u32,
               const unsigned* __restrict__ dflags,
               _Float16* __restrict__ out)        // [M][512] f16
{
    extern __shared__ char lds_raw[];
    _Float16* ldsA  = (_Float16*)lds_raw;                      // [16][8][64][8] 128KB (gate1)
    _Float16* ldsA2 = (_Float16*)(lds_raw + 131072);           // [16][64][8] 16KB (gate2 kc0)
    _Float16* h16   = (_Float16*)(lds_raw + 131072 + 16384);   // [2][4][264] 4224B

    const int tid = threadIdx.x;
    const int bid = blockIdx.x;
    const int dir = bid >> 4;
    const int b0  = (bid & 15) * 4;
    const int w    = tid >> 6;
    const int lane = tid & 63;
    const int n    = lane & 15;
    const int kg   = lane >> 4;
    const int j0   = w * 16 + kg * 4;
    const _Float16* __restrict__ PA = dir ? PAb : PAf;
    const bool l64 = (dflags[0] & 2u) != 0u;
    const int mylen = (n < 4) ? (int)(l64 ? len_u32[2 * (b0 + n)] : len_u32[b0 + n]) : 0;

    // stage gate-1 frags (fg = w*32+8+kc) into ldsA
    for (int chunk = tid; chunk < 8192; chunk += 1024) {
        int lfrag = chunk >> 6, lane_s = chunk & 63;
        int w_s = lfrag >> 3, kc_s = lfrag & 7;
        int fg = w_s * 32 + 8 + kc_s;
        *(uint4*)(ldsA + (size_t)chunk * 8) = *(const uint4*)(PA + ((size_t)fg * 64 + lane_s) * 8);
    }
    // stage gate-2 kc0 frags (fg = w*32+16) into ldsA2
    {
        int chunk = tid;   // 0..1023, exactly one per thread
        int w_s = chunk >> 6, lane_s = chunk & 63;
        int fg = w_s * 32 + 16;
        *(uint4*)(ldsA2 + (size_t)chunk * 8) = *(const uint4*)(PA + ((size_t)fg * 64 + lane_s) * 8);
    }
    // regs: gate-0 kc0-3
    uint4 Ar[4];
    #pragma unroll
    for (int kc = 0; kc < 4; ++kc)
        Ar[kc] = *(const uint4*)(PA + ((size_t)(w * 32 + kc) * 64 + lane) * 8);

    float c[4] = {0.f, 0.f, 0.f, 0.f};
    float hreg[4] = {0.f, 0.f, 0.f, 0.f};
    if (n < 4) {
        v4hf z = {(_Float16)0.f, (_Float16)0.f, (_Float16)0.f, (_Float16)0.f};
        *(uint2*)(h16 + 0 * 1056 + n * 264 + j0) = __builtin_bit_cast(uint2, z);
    }
    __syncthreads();

    for (int t = 0; t < Tq; ++t) {
        const int teff = dir ? (Tq - 1 - t) : t;
        const int par = t & 1;
        const _Float16* hrd = h16 + par * 1056;

        v4f acc0 = {0.f, 0.f, 0.f, 0.f};
        v4f acc1 = {0.f, 0.f, 0.f, 0.f};
        v4f acc2 = {0.f, 0.f, 0.f, 0.f};
        v4f acc3 = {0.f, 0.f, 0.f, 0.f};
        #pragma unroll
        for (int kc = 0; kc < 8; ++kc) {
            v8hf B;
            if (n < 4) {
                uint4 hb = *(const uint4*)(hrd + n * 264 + kc * 32 + kg * 8);
                B = __builtin_bit_cast(v8hf, hb);
            } else {
                uint4 z = {0u, 0u, 0u, 0u};
                B = __builtin_bit_cast(v8hf, z);
            }
            v8hf A0;
            if (kc < 4) A0 = __builtin_bit_cast(v8hf, Ar[kc]);
            else A0 = __builtin_bit_cast(v8hf, *(const uint4*)(PA + ((size_t)(w * 32 + kc) * 64 + lane) * 8));
            acc0 = __builtin_amdgcn_mfma_f32_16x16x32_f16(A0, B, acc0, 0, 0, 0);
            v8hf A1 = __builtin_bit_cast(v8hf, *(const uint4*)(ldsA + ((size_t)(w * 8 + kc) * 64 + lane) * 8));
            acc1 = __builtin_amdgcn_mfma_f32_16x16x32_f16(A1, B, acc1, 0, 0, 0);
            v8hf A2;
            if (kc == 0) A2 = __builtin_bit_cast(v8hf, *(const uint4*)(ldsA2 + ((size_t)(w * 64 + lane)) * 8));
            else A2 = __builtin_bit_cast(v8hf, *(const uint4*)(PA + ((size_t)(w * 32 + 16 + kc) * 64 + lane) * 8));
            acc2 = __builtin_amdgcn_mfma_f32_16x16x32_f16(A2, B, acc2, 0, 0, 0);
            v8hf A3 = __builtin_bit_cast(v8hf, *(const uint4*)(PA + ((size_t)(w * 32 + 24 + kc) * 64 + lane) * 8));
            acc3 = __builtin_amdgcn_mfma_f32_16x16x32_f16(A3, B, acc3, 0, 0, 0);
        }
        // in-lane LSTM update: lane (n<4, kg) owns units j0..j0+3 of batch b0+n
        if (n < 4) {
            const _Float16* xr = xg + ((size_t)(b0 + n) * Tq + teff) * 2048 + dir * 1024 + j0;
            v4hf x0 = __builtin_bit_cast(v4hf, *(const uint2*)(xr));
            v4hf x1 = __builtin_bit_cast(v4hf, *(const uint2*)(xr + 256));
            v4hf x2 = __builtin_bit_cast(v4hf, *(const uint2*)(xr + 512));
            v4hf x3 = __builtin_bit_cast(v4hf, *(const uint2*)(xr + 768));
            const bool m = (teff < mylen);
            v4hf hh4;
            #pragma unroll
            for (int r = 0; r < 4; ++r) {
                float g0 = (float)x0[r] + acc0[r];
                float g1 = (float)x1[r] + acc1[r];
                float g2 = (float)x2[r] + acc2[r];
                float g3 = (float)x3[r] + acc3[r];
                float ig = sigmoidf_(g0), fg = sigmoidf_(g1);
                float gg = tanhf_(g2), og = sigmoidf_(g3);
                float cn = fg * c[r] + ig * gg;
                float hn = og * tanhf_(cn);
                float hm = m ? hn : hreg[r];
                c[r] = m ? cn : c[r];
                hreg[r] = hm;
                hh4[r] = (_Float16)hm;
            }
            uint2 hw = __builtin_bit_cast(uint2, hh4);
            *(uint2*)(h16 + (par ^ 1) * 1056 + n * 264 + j0) = hw;
            size_t orow = (size_t)(b0 + n) * Tq + teff;
            *(uint2*)(out + orow * 512 + dir * 256 + j0) = hw;
        }
        __syncthreads();
    }
}

extern "C" void kernel_launch(void* const* d_in, const int* in_sizes, int n_in,
                              void* d_out, int out_size, void* d_ws, size_t ws_size,
                              hipStream_t stream)
{
    const unsigned* words  = (const unsigned*)d_in[0];
    const unsigned* lens   = (const unsigned*)d_in[1];
    const float* emb     = (const float*)d_in[2];
    const float* l1f_Wih = (const float*)d_in[3];
    const float* l1f_Whh = (const float*)d_in[4];
    const float* l1f_bih = (const float*)d_in[5];
    const float* l1f_bhh = (const float*)d_in[6];
    const float* l1b_Wih = (const float*)d_in[7];
    const float* l1b_Whh = (const float*)d_in[8];
    const float* l1b_bih = (const float*)d_in[9];
    const float* l1b_bhh = (const float*)d_in[10];
    const float* l2f_Wih = (const float*)d_in[11];
    const float* l2f_Whh = (const float*)d_in[12];
    const float* l2f_bih = (const float*)d_in[13];
    const float* l2f_bhh = (const float*)d_in[14];
    const float* l2b_Wih = (const float*)d_in[15];
    const float* l2b_Whh = (const float*)d_in[16];
    const float* l2b_bih = (const float*)d_in[17];
    const float* l2b_bhh = (const float*)d_in[18];
    const float* cls_W   = (const float*)d_in[19];
    const float* cls_b   = (const float*)d_in[20];
    (void)in_sizes; (void)n_in; (void)out_size; (void)ws_size;

    char* ws = (char*)d_ws;
    size_t off = 0;
    auto alloc = [&](size_t b) { void* p = ws + off; off += (b + 255) & ~(size_t)255; return p; };
    _Float16*  xg = (_Float16*)alloc((size_t)Mq * 2048 * 2);  // 128 MiB
    _Float16*  o1 = (_Float16*)alloc((size_t)Mq * 512 * 2);   // 32 MiB
    _Float16*  o2 = (_Float16*)alloc((size_t)Mq * 512 * 2);   // 32 MiB
    _Float16* PAk = (_Float16*)alloc((size_t)4 * 262144 * 2); // 2 MiB lstm A-frags
    _Float16* PB1 = (_Float16*)alloc((size_t)2 * 131072 * 2); // 512 KB l1 B-frags
    _Float16* PB2 = (_Float16*)alloc((size_t)2 * 524288 * 2); // 2 MiB l2 B-frags
    _Float16* PBc = (_Float16*)alloc((size_t)131072 * 2);     // 256 KB cls B-frags
    float* biasbuf = (float*)alloc((size_t)4 * 1024 * 4);
    unsigned* dflags = (unsigned*)alloc(256);

    _Float16* PA1f = PAk;
    _Float16* PA1b = PAk + 262144;
    _Float16* PA2f = PAk + 2 * 262144;
    _Float16* PA2b = PAk + 3 * 262144;

    const size_t ldsBytes = 131072 + 16384 + 4224;   // 151680
    hipFuncSetAttribute((const void*)lstm_mfma, hipFuncAttributeMaxDynamicSharedMemorySize, (int)ldsBytes);

    detect_int64<<<1, 256, 0, stream>>>(words, lens, dflags);
    bias_kernel<<<dim3(16), 256, 0, stream>>>(l1f_bih, l1f_bhh, l1b_bih, l1b_bhh,
                                              l2f_bih, l2f_bhh, l2b_bih, l2b_bhh, biasbuf);
    pack_whh_mfma<<<dim3(128), 256, 0, stream>>>(l1f_Whh, PA1f);
    pack_whh_mfma<<<dim3(128), 256, 0, stream>>>(l1b_Whh, PA1b);
    pack_whh_mfma<<<dim3(128), 256, 0, stream>>>(l2f_Whh, PA2f);
    pack_whh_mfma<<<dim3(128), 256, 0, stream>>>(l2b_Whh, PA2b);
    pack_w_bfrag<<<dim3(64), 256, 0, stream>>>(l1f_Wih, PB1, 1024, 128, 16384);
    pack_w_bfrag<<<dim3(64), 256, 0, stream>>>(l1b_Wih, PB1 + 131072, 1024, 128, 16384);
    pack_w_bfrag<<<dim3(256), 256, 0, stream>>>(l2f_Wih, PB2, 1024, 512, 65536);
    pack_w_bfrag<<<dim3(256), 256, 0, stream>>>(l2b_Wih, PB2 + 524288, 1024, 512, 65536);
    pack_w_bfrag<<<dim3(64), 256, 0, stream>>>(cls_W, PBc, NTAGS, 512, 16384);

    // ---- layer 1 ----
    gemm_mfma<2, 1><<<dim3(8, Mq / 64), 256, 0, stream>>>(nullptr, words, emb, dflags,
        PB1, biasbuf, xg, 2048, 128, 2048);
    lstm_mfma<<<32, 1024, ldsBytes, stream>>>(xg, PA1f, PA1b, lens, dflags, o1);
    // ---- layer 2 ----
    gemm_mfma<0, 1><<<dim3(8, Mq / 64), 256, 0, stream>>>(o1, nullptr, nullptr, dflags,
        PB2, biasbuf + 2048, xg, 2048, 512, 2048);
    lstm_mfma<<<32, 1024, ldsBytes, stream>>>(xg, PA2f, PA2b, lens, dflags, o2);
    // ---- classifier -> d_out (f32) ----
    gemm_mfma<0, 0><<<dim3(1, Mq / 64), 256, 0, stream>>>(o2, nullptr, nullptr, dflags,
        PBc, cls_b, d_out, NTAGS, 512, NTAGS);
}

// Round 21
// 4129.574 us; speedup vs baseline: 1.3345x; 1.3345x over previous
//
#include <hip/hip_runtime.h>
#include <hip/hip_bf16.h>

#define Bq 64
#define Tq 512
#define Eq 128
#define Hq 256
#define NTAGS 50
#define Mq (Bq*Tq)   // 32768

typedef _Float16 v8hf __attribute__((ext_vector_type(8)));
typedef float v4f __attribute__((ext_vector_type(4)));

__device__ __forceinline__ float sigmoidf_(float x) { return 1.f / (1.f + __expf(-x)); }
__device__ __forceinline__ float tanhf_(float x) {
    float e = __expf(2.f * x);
    return 1.f - 2.f / (e + 1.f);
}

// ---------------- dtype detection: int32 vs int64 for words/lengths ----------------
__global__ void detect_int64(const unsigned* __restrict__ words,
                             const unsigned* __restrict__ lens,
                             unsigned* __restrict__ dflags) {
    __shared__ int wbad, lbad, wnz, lnz;
    if (threadIdx.x == 0) { wbad = 0; lbad = 0; wnz = 0; lnz = 0; }
    __syncthreads();
    for (int i = threadIdx.x; i < 16384; i += blockDim.x) {
        if (words[2 * i + 1] != 0u) wbad = 1;
        if (words[2 * i] != 0u) wnz = 1;
    }
    for (int i = threadIdx.x; i < 32; i += blockDim.x) {
        if (lens[2 * i + 1] != 0u) lbad = 1;
        if (lens[2 * i] != 0u) lnz = 1;
    }
    __syncthreads();
    if (threadIdx.x == 0) {
        unsigned f = 0;
        if (!wbad && wnz) f |= 1u;
        if (!lbad && lnz) f |= 2u;
        dflags[0] = f;
    }
}

// ---------------- bias: bias[l][d][n] = bih + bhh ----------------
__global__ void bias_kernel(const float* b1f_ih, const float* b1f_hh,
                            const float* b1b_ih, const float* b1b_hh,
                            const float* b2f_ih, const float* b2f_hh,
                            const float* b2b_ih, const float* b2b_hh,
                            float* bias) {   // [4][1024]: l1f,l1b,l2f,l2b
    int i = blockIdx.x * blockDim.x + threadIdx.x;
    if (i >= 4096) return;
    int l = i >> 11, d = (i >> 10) & 1, nn = i & 1023;
    float v;
    if (l == 0) v = d ? (b1b_ih[nn] + b1b_hh[nn]) : (b1f_ih[nn] + b1f_hh[nn]);
    else        v = d ? (b2b_ih[nn] + b2b_hh[nn]) : (b2f_ih[nn] + b2f_hh[nn]);
    bias[i] = v;
}

// ---------------- Whh -> MFMA A-fragment packing (round-19 layout, verified) ----------------
// frag fg = w*32 + mtl*8 + kc; lane holds A[(w*4+mtl)*16 + (lane&15)][kc*32+(lane>>4)*8+i]
__global__ void pack_whh_mfma(const float* __restrict__ W, _Float16* __restrict__ PA) {
    int t = blockIdx.x * 256 + threadIdx.x;   // chunk id 0..32767
    if (t >= 32768) return;
    int fg = t >> 6, lane = t & 63;
    int w = fg >> 5, rem = fg & 31, mtl = rem >> 3, kc = rem & 7;
    int grow = (w * 4 + mtl) * 16 + (lane & 15);
    int kb = kc * 32 + (lane >> 4) * 8;
    _Float16 h8[8];
    #pragma unroll
    for (int i = 0; i < 8; ++i) h8[i] = (_Float16)W[(size_t)grow * 256 + kb + i];
    *(uint4*)(PA + ((size_t)fg * 64 + lane) * 8) = *(const uint4*)h8;
}

// ---------------- generic W[N][K] f32 -> MFMA B-fragment packing (verified r19) ----------------
__global__ void pack_w_bfrag(const float* __restrict__ W, _Float16* __restrict__ PB,
                             int Nvalid, int K, int nchunks) {
    int t = blockIdx.x * 256 + threadIdx.x;
    if (t >= nchunks) return;
    int fg = t >> 6, lane = t & 63;
    int kcn = K >> 5;
    int ntile = fg / kcn, kc = fg % kcn;
    int n = ntile * 16 + (lane & 15);
    int kb = kc * 32 + (lane >> 4) * 8;
    _Float16 h8[8];
    #pragma unroll
    for (int i = 0; i < 8; ++i)
        h8[i] = (n < Nvalid) ? (_Float16)W[(size_t)n * K + kb + i] : (_Float16)0.f;
    *(uint4*)(PB + ((size_t)fg * 64 + lane) * 8) = *(const uint4*)h8;
}

// ---------------- MFMA GEMM (verified round 19, unchanged) ----------------
template<int AMODE, int OUTT>
__global__ __launch_bounds__(256)
void gemm_mfma(const _Float16* __restrict__ Asrc, const unsigned* __restrict__ words_u32,
               const float* __restrict__ emb, const unsigned* __restrict__ dflags,
               const _Float16* __restrict__ PB, const float* __restrict__ bias,
               void* __restrict__ Cptr, int Nstr, int K, int Nvalid)
{
    __shared__ _Float16 At[64 * 40];
    const int tid = threadIdx.x;
    const int w = tid >> 6, lane = tid & 63;
    const int n0w = blockIdx.x * 256 + w * 64;
    const int m0 = blockIdx.y * 64;
    const int srow = tid >> 2, sseg = tid & 3;
    const int kcn = K >> 5;
    const int ntb = n0w >> 4;
    bool w64 = false;
    if (AMODE == 2) w64 = (dflags[0] & 1u) != 0u;

    v4f acc[4][4] = {};
    for (int kc0 = 0; kc0 < kcn; ++kc0) {
        if (AMODE == 0) {
            uint4 v = *(const uint4*)(Asrc + (size_t)(m0 + srow) * K + kc0 * 32 + sseg * 8);
            *(uint4*)(At + srow * 40 + sseg * 8) = v;
        } else {
            int wd = (int)(w64 ? words_u32[2 * (m0 + srow)] : words_u32[m0 + srow]);
            const float* src = emb + (size_t)wd * Eq + kc0 * 32 + sseg * 8;
            float4 v0 = *(const float4*)src;
            float4 v1 = *(const float4*)(src + 4);
            _Float16 h8[8] = {(_Float16)v0.x, (_Float16)v0.y, (_Float16)v0.z, (_Float16)v0.w,
                              (_Float16)v1.x, (_Float16)v1.y, (_Float16)v1.z, (_Float16)v1.w};
            *(uint4*)(At + srow * 40 + sseg * 8) = *(const uint4*)h8;
        }
        __syncthreads();
        v8hf Bf[4];
        #pragma unroll
        for (int nf = 0; nf < 4; ++nf) {
            size_t fg = (size_t)(ntb + nf) * kcn + kc0;
            Bf[nf] = __builtin_bit_cast(v8hf, *(const uint4*)(PB + (fg * 64 + lane) * 8));
        }
        #pragma unroll
        for (int mf = 0; mf < 4; ++mf) {
            v8hf Af = __builtin_bit_cast(v8hf,
                *(const uint4*)(At + (mf * 16 + (lane & 15)) * 40 + (lane >> 4) * 8));
            #pragma unroll
            for (int nf = 0; nf < 4; ++nf)
                acc[mf][nf] = __builtin_amdgcn_mfma_f32_16x16x32_f16(Af, Bf[nf], acc[mf][nf], 0, 0, 0);
        }
        __syncthreads();
    }
    #pragma unroll
    for (int nf = 0; nf < 4; ++nf) {
        int colb = n0w + nf * 16 + (lane & 15);
        float bb = (colb < Nvalid) ? bias[colb] : 0.f;
        #pragma unroll
        for (int mf = 0; mf < 4; ++mf) {
            int rowb = m0 + mf * 16 + (lane >> 4) * 4;
            #pragma unroll
            for (int r = 0; r < 4; ++r) {
                float v = acc[mf][nf][r] + bb;
                if (OUTT == 1) {
                    ((_Float16*)Cptr)[(size_t)(rowb + r) * Nstr + colb] = (_Float16)v;
                } else {
                    if (colb < Nvalid)
                        ((float*)Cptr)[(size_t)(rowb + r) * Nstr + colb] = v;
                }
            }
        }
    }
}

// ---------------- MFMA LSTM (round-19 structure, verified) + ldsA3 extension ----------------
// 32 blocks x 1024 threads (16 waves). Wave w owns gate-rows [w*64, w*64+64)
// as 4 M-tiles x 8 K-chunks. Residency: regs mtl0/kc0-3, LDS mtl1/all,
// ldsA3 mtl2/kc0 for waves 0..10 (12KB headroom), stream the rest (309 KB/step).
// Update spread over ALL 1024 threads via gbuf (r20 in-lane variant regressed:
// 16/64-lane divergent update cost > barrier savings). 2 barriers/step.
__global__ __launch_bounds__(1024)
void lstm_mfma(const _Float16* __restrict__ xg,   // [M][2048] f16, col = dir*1024+g*256+j
               const _Float16* __restrict__ PAf, const _Float16* __restrict__ PAb,
               const unsigned* __restrict__ len_u32,
               const unsigned* __restrict__ dflags,
               _Float16* __restrict__ out)        // [M][512] f16
{
    extern __shared__ char lds_raw[];
    _Float16* ldsA  = (_Float16*)lds_raw;                      // 128KB: [128][64][8] (mtl1)
    float*    gbuf  = (float*)(lds_raw + 131072);              // [4][1032] f32 = 16512B
    _Float16* h16   = (_Float16*)(lds_raw + 131072 + 16512);   // [2][4][264] = 4224B
    _Float16* ldsA3 = (_Float16*)(lds_raw + 131072 + 16512 + 4224); // [11][64][8] = 11264B (mtl2/kc0, waves 0..10)

    const int tid = threadIdx.x;
    const int bid = blockIdx.x;
    const int dir = bid >> 4;
    const int b0  = (bid & 15) * 4;
    const int w    = tid >> 6;
    const int lane = tid & 63;
    const int n    = lane & 15;
    const int kg   = lane >> 4;
    const int bu   = tid >> 8;
    const int j    = tid & 255;
    const _Float16* __restrict__ PA = dir ? PAb : PAf;
    const bool l64 = (dflags[0] & 2u) != 0u;
    const int mylen = (int)(l64 ? len_u32[2 * (b0 + bu)] : len_u32[b0 + bu]);

    // stage mtl1 frags (fg = w*32+8+kc) into ldsA
    for (int chunk = tid; chunk < 8192; chunk += 1024) {
        int lfrag = chunk >> 6, lane_s = chunk & 63;
        int w_s = lfrag >> 3, kc_s = lfrag & 7;
        int fg = w_s * 32 + 8 + kc_s;
        *(uint4*)(ldsA + (size_t)chunk * 8) = *(const uint4*)(PA + ((size_t)fg * 64 + lane_s) * 8);
    }
    // stage mtl2/kc0 frags for waves 0..10 into ldsA3
    if (tid < 704) {
        int w_s = tid >> 6, lane_s = tid & 63;
        int fg = w_s * 32 + 16;   // mtl2, kc0
        *(uint4*)(ldsA3 + (size_t)tid * 8) = *(const uint4*)(PA + ((size_t)fg * 64 + lane_s) * 8);
    }
    // regs: mtl0 kc0-3
    uint4 Ar[4];
    #pragma unroll
    for (int kc = 0; kc < 4; ++kc)
        Ar[kc] = *(const uint4*)(PA + ((size_t)(w * 32 + kc) * 64 + lane) * 8);

    float c = 0.f, hreg = 0.f;
    h16[0 * 1056 + bu * 264 + j] = (_Float16)0.f;
    __syncthreads();

    for (int t = 0; t < Tq; ++t) {
        const int teff = dir ? (Tq - 1 - t) : t;
        const int par = t & 1;
        const _Float16* hrd = h16 + par * 1056;

        const _Float16* xr = xg + ((size_t)(b0 + bu) * Tq + teff) * 2048 + dir * 1024 + j;
        float xv0 = (float)xr[0], xv1 = (float)xr[256], xv2 = (float)xr[512], xv3 = (float)xr[768];

        v4f acc0 = {0.f, 0.f, 0.f, 0.f};
        v4f acc1 = {0.f, 0.f, 0.f, 0.f};
        v4f acc2 = {0.f, 0.f, 0.f, 0.f};
        v4f acc3 = {0.f, 0.f, 0.f, 0.f};
        #pragma unroll
        for (int kc = 0; kc < 8; ++kc) {
            v8hf B;
            if (n < 4) {
                uint4 hb = *(const uint4*)(hrd + n * 264 + kc * 32 + kg * 8);
                B = __builtin_bit_cast(v8hf, hb);
            } else {
                uint4 z = {0u, 0u, 0u, 0u};
                B = __builtin_bit_cast(v8hf, z);
            }
            v8hf A0;
            if (kc < 4) A0 = __builtin_bit_cast(v8hf, Ar[kc]);
            else A0 = __builtin_bit_cast(v8hf, *(const uint4*)(PA + ((size_t)(w * 32 + kc) * 64 + lane) * 8));
            acc0 = __builtin_amdgcn_mfma_f32_16x16x32_f16(A0, B, acc0, 0, 0, 0);
            v8hf A1 = __builtin_bit_cast(v8hf, *(const uint4*)(ldsA + ((size_t)(w * 8 + kc) * 64 + lane) * 8));
            acc1 = __builtin_amdgcn_mfma_f32_16x16x32_f16(A1, B, acc1, 0, 0, 0);
            v8hf A2;
            if (kc == 0 && w < 11)
                A2 = __builtin_bit_cast(v8hf, *(const uint4*)(ldsA3 + ((size_t)(w * 64 + lane)) * 8));
            else
                A2 = __builtin_bit_cast(v8hf, *(const uint4*)(PA + ((size_t)(w * 32 + 16 + kc) * 64 + lane) * 8));
            acc2 = __builtin_amdgcn_mfma_f32_16x16x32_f16(A2, B, acc2, 0, 0, 0);
            v8hf A3 = __builtin_bit_cast(v8hf, *(const uint4*)(PA + ((size_t)(w * 32 + 24 + kc) * 64 + lane) * 8));
            acc3 = __builtin_amdgcn_mfma_f32_16x16x32_f16(A3, B, acc3, 0, 0, 0);
        }
        if (n < 4) {
            float* gp = gbuf + n * 1032 + w * 64 + kg * 4;
            gp[0]  = acc0[0]; gp[1]  = acc0[1]; gp[2]  = acc0[2]; gp[3]  = acc0[3];
            gp[16] = acc1[0]; gp[17] = acc1[1]; gp[18] = acc1[2]; gp[19] = acc1[3];
            gp[32] = acc2[0]; gp[33] = acc2[1]; gp[34] = acc2[2]; gp[35] = acc2[3];
            gp[48] = acc3[0]; gp[49] = acc3[1]; gp[50] = acc3[2]; gp[51] = acc3[3];
        }
        __syncthreads();
        {
            float g0 = xv0 + gbuf[bu * 1032 + 0 * 256 + j];
            float g1 = xv1 + gbuf[bu * 1032 + 1 * 256 + j];
            float g2 = xv2 + gbuf[bu * 1032 + 2 * 256 + j];
            float g3 = xv3 + gbuf[bu * 1032 + 3 * 256 + j];
            float ig = sigmoidf_(g0), fg = sigmoidf_(g1);
            float gg = tanhf_(g2), og = sigmoidf_(g3);
            float cn = fg * c + ig * gg;
            float hn = og * tanhf_(cn);
            bool m = (teff < mylen);
            float hm = m ? hn : hreg;
            c = m ? cn : c;
            hreg = hm;
            h16[(par ^ 1) * 1056 + bu * 264 + j] = (_Float16)hm;
            size_t orow = (size_t)(b0 + bu) * Tq + teff;
            out[orow * 512 + dir * 256 + j] = (_Float16)hm;
        }
        __syncthreads();
    }
}

extern "C" void kernel_launch(void* const* d_in, const int* in_sizes, int n_in,
                              void* d_out, int out_size, void* d_ws, size_t ws_size,
                              hipStream_t stream)
{
    const unsigned* words  = (const unsigned*)d_in[0];
    const unsigned* lens   = (const unsigned*)d_in[1];
    const float* emb     = (const float*)d_in[2];
    const float* l1f_Wih = (const float*)d_in[3];
    const float* l1f_Whh = (const float*)d_in[4];
    const float* l1f_bih = (const float*)d_in[5];
    const float* l1f_bhh = (const float*)d_in[6];
    const float* l1b_Wih = (const float*)d_in[7];
    const float* l1b_Whh = (const float*)d_in[8];
    const float* l1b_bih = (const float*)d_in[9];
    const float* l1b_bhh = (const float*)d_in[10];
    const float* l2f_Wih = (const float*)d_in[11];
    const float* l2f_Whh = (const float*)d_in[12];
    const float* l2f_bih = (const float*)d_in[13];
    const float* l2f_bhh = (const float*)d_in[14];
    const float* l2b_Wih = (const float*)d_in[15];
    const float* l2b_Whh = (const float*)d_in[16];
    const float* l2b_bih = (const float*)d_in[17];
    const float* l2b_bhh = (const float*)d_in[18];
    const float* cls_W   = (const float*)d_in[19];
    const float* cls_b   = (const float*)d_in[20];
    (void)in_sizes; (void)n_in; (void)out_size; (void)ws_size;

    char* ws = (char*)d_ws;
    size_t off = 0;
    auto alloc = [&](size_t b) { void* p = ws + off; off += (b + 255) & ~(size_t)255; return p; };
    _Float16*  xg = (_Float16*)alloc((size_t)Mq * 2048 * 2);  // 128 MiB
    _Float16*  o1 = (_Float16*)alloc((size_t)Mq * 512 * 2);   // 32 MiB
    _Float16*  o2 = (_Float16*)alloc((size_t)Mq * 512 * 2);   // 32 MiB
    _Float16* PAk = (_Float16*)alloc((size_t)4 * 262144 * 2); // 2 MiB lstm A-frags
    _Float16* PB1 = (_Float16*)alloc((size_t)2 * 131072 * 2); // 512 KB l1 B-frags
    _Float16* PB2 = (_Float16*)alloc((size_t)2 * 524288 * 2); // 2 MiB l2 B-frags
    _Float16* PBc = (_Float16*)alloc((size_t)131072 * 2);     // 256 KB cls B-frags
    float* biasbuf = (float*)alloc((size_t)4 * 1024 * 4);
    unsigned* dflags = (unsigned*)alloc(256);

    _Float16* PA1f = PAk;
    _Float16* PA1b = PAk + 262144;
    _Float16* PA2f = PAk + 2 * 262144;
    _Float16* PA2b = PAk + 3 * 262144;

    const size_t ldsBytes = 131072 + 16512 + 4224 + 11264;   // 163072 <= 163840
    hipFuncSetAttribute((const void*)lstm_mfma, hipFuncAttributeMaxDynamicSharedMemorySize, (int)ldsBytes);

    detect_int64<<<1, 256, 0, stream>>>(words, lens, dflags);
    bias_kernel<<<dim3(16), 256, 0, stream>>>(l1f_bih, l1f_bhh, l1b_bih, l1b_bhh,
                                              l2f_bih, l2f_bhh, l2b_bih, l2b_bhh, biasbuf);
    pack_whh_mfma<<<dim3(128), 256, 0, stream>>>(l1f_Whh, PA1f);
    pack_whh_mfma<<<dim3(128), 256, 0, stream>>>(l1b_Whh, PA1b);
    pack_whh_mfma<<<dim3(128), 256, 0, stream>>>(l2f_Whh, PA2f);
    pack_whh_mfma<<<dim3(128), 256, 0, stream>>>(l2b_Whh, PA2b);
    pack_w_bfrag<<<dim3(64), 256, 0, stream>>>(l1f_Wih, PB1, 1024, 128, 16384);
    pack_w_bfrag<<<dim3(64), 256, 0, stream>>>(l1b_Wih, PB1 + 131072, 1024, 128, 16384);
    pack_w_bfrag<<<dim3(256), 256, 0, stream>>>(l2f_Wih, PB2, 1024, 512, 65536);
    pack_w_bfrag<<<dim3(256), 256, 0, stream>>>(l2b_Wih, PB2 + 524288, 1024, 512, 65536);
    pack_w_bfrag<<<dim3(64), 256, 0, stream>>>(cls_W, PBc, NTAGS, 512, 16384);

    // ---- layer 1 ----
    gemm_mfma<2, 1><<<dim3(8, Mq / 64), 256, 0, stream>>>(nullptr, words, emb, dflags,
        PB1, biasbuf, xg, 2048, 128, 2048);
    lstm_mfma<<<32, 1024, ldsBytes, stream>>>(xg, PA1f, PA1b, lens, dflags, o1);
    // ---- layer 2 ----
    gemm_mfma<0, 1><<<dim3(8, Mq / 64), 256, 0, stream>>>(o1, nullptr, nullptr, dflags,
        PB2, biasbuf + 2048, xg, 2048, 512, 2048);
    lstm_mfma<<<32, 1024, ldsBytes, stream>>>(xg, PA2f, PA2b, lens, dflags, o2);
    // ---- classifier -> d_out (f32) ----
    gemm_mfma<0, 0><<<dim3(1, Mq / 64), 256, 0, stream>>>(o2, nullptr, nullptr, dflags,
        PBc, cls_b, d_out, NTAGS, 512, NTAGS);
}

// Round 22
// 3799.106 us; speedup vs baseline: 1.4506x; 1.0870x over previous
//
#include <hip/hip_runtime.h>
#include <hip/hip_bf16.h>

#define Bq 64
#define Tq 512
#define Eq 128
#define Hq 256
#define NTAGS 50
#define Mq (Bq*Tq)   // 32768

typedef _Float16 v8hf __attribute__((ext_vector_type(8)));
typedef float v4f __attribute__((ext_vector_type(4)));

__device__ __forceinline__ float sigmoidf_(float x) { return 1.f / (1.f + __expf(-x)); }
__device__ __forceinline__ float tanhf_(float x) {
    float e = __expf(2.f * x);
    return 1.f - 2.f / (e + 1.f);
}

// ---------------- dtype detection: int32 vs int64 for words/lengths ----------------
__global__ void detect_int64(const unsigned* __restrict__ words,
                             const unsigned* __restrict__ lens,
                             unsigned* __restrict__ dflags) {
    __shared__ int wbad, lbad, wnz, lnz;
    if (threadIdx.x == 0) { wbad = 0; lbad = 0; wnz = 0; lnz = 0; }
    __syncthreads();
    for (int i = threadIdx.x; i < 16384; i += blockDim.x) {
        if (words[2 * i + 1] != 0u) wbad = 1;
        if (words[2 * i] != 0u) wnz = 1;
    }
    for (int i = threadIdx.x; i < 32; i += blockDim.x) {
        if (lens[2 * i + 1] != 0u) lbad = 1;
        if (lens[2 * i] != 0u) lnz = 1;
    }
    __syncthreads();
    if (threadIdx.x == 0) {
        unsigned f = 0;
        if (!wbad && wnz) f |= 1u;
        if (!lbad && lnz) f |= 2u;
        dflags[0] = f;
    }
}

// ---------------- bias: bias[l][d][n] = bih + bhh ----------------
__global__ void bias_kernel(const float* b1f_ih, const float* b1f_hh,
                            const float* b1b_ih, const float* b1b_hh,
                            const float* b2f_ih, const float* b2f_hh,
                            const float* b2b_ih, const float* b2b_hh,
                            float* bias) {   // [4][1024]: l1f,l1b,l2f,l2b
    int i = blockIdx.x * blockDim.x + threadIdx.x;
    if (i >= 4096) return;
    int l = i >> 11, d = (i >> 10) & 1, nn = i & 1023;
    float v;
    if (l == 0) v = d ? (b1b_ih[nn] + b1b_hh[nn]) : (b1f_ih[nn] + b1f_hh[nn]);
    else        v = d ? (b2b_ih[nn] + b2b_hh[nn]) : (b2f_ih[nn] + b2f_hh[nn]);
    bias[i] = v;
}

// ---------------- Whh -> MFMA A-fragment packing (verified round 18/19) ----------------
__global__ void pack_whh_mfma(const float* __restrict__ W, _Float16* __restrict__ PA) {
    int t = blockIdx.x * 256 + threadIdx.x;   // chunk id 0..32767
    if (t >= 32768) return;
    int fg = t >> 6, lane = t & 63;
    int w = fg >> 5, rem = fg & 31, mtl = rem >> 3, kc = rem & 7;
    int grow = (w * 4 + mtl) * 16 + (lane & 15);
    int kb = kc * 32 + (lane >> 4) * 8;
    _Float16 h8[8];
    #pragma unroll
    for (int i = 0; i < 8; ++i) h8[i] = (_Float16)W[(size_t)grow * 256 + kb + i];
    *(uint4*)(PA + ((size_t)fg * 64 + lane) * 8) = *(const uint4*)h8;
}

// ---------------- generic W[N][K] f32 -> MFMA B-fragment packing (verified r19) ----------------
__global__ void pack_w_bfrag(const float* __restrict__ W, _Float16* __restrict__ PB,
                             int Nvalid, int K, int nchunks) {
    int t = blockIdx.x * 256 + threadIdx.x;
    if (t >= nchunks) return;
    int fg = t >> 6, lane = t & 63;
    int kcn = K >> 5;
    int ntile = fg / kcn, kc = fg % kcn;
    int n = ntile * 16 + (lane & 15);
    int kb = kc * 32 + (lane >> 4) * 8;
    _Float16 h8[8];
    #pragma unroll
    for (int i = 0; i < 8; ++i)
        h8[i] = (n < Nvalid) ? (_Float16)W[(size_t)n * K + kb + i] : (_Float16)0.f;
    *(uint4*)(PB + ((size_t)fg * 64 + lane) * 8) = *(const uint4*)h8;
}

// ---------------- MFMA GEMM: C[M, Nstr] = A[M,K] @ W^T + bias (verified r19) ----------------
template<int AMODE, int OUTT>
__global__ __launch_bounds__(256)
void gemm_mfma(const _Float16* __restrict__ Asrc, const unsigned* __restrict__ words_u32,
               const float* __restrict__ emb, const unsigned* __restrict__ dflags,
               const _Float16* __restrict__ PB, const float* __restrict__ bias,
               void* __restrict__ Cptr, int Nstr, int K, int Nvalid)
{
    __shared__ _Float16 At[64 * 40];
    const int tid = threadIdx.x;
    const int w = tid >> 6, lane = tid & 63;
    const int n0w = blockIdx.x * 256 + w * 64;
    const int m0 = blockIdx.y * 64;
    const int srow = tid >> 2, sseg = tid & 3;
    const int kcn = K >> 5;
    const int ntb = n0w >> 4;           // wave's base n-tile
    bool w64 = false;
    if (AMODE == 2) w64 = (dflags[0] & 1u) != 0u;

    v4f acc[4][4] = {};
    for (int kc0 = 0; kc0 < kcn; ++kc0) {
        // stage A[64][32] -> LDS (f16, padded rows of 40)
        if (AMODE == 0) {
            uint4 v = *(const uint4*)(Asrc + (size_t)(m0 + srow) * K + kc0 * 32 + sseg * 8);
            *(uint4*)(At + srow * 40 + sseg * 8) = v;
        } else {
            int wd = (int)(w64 ? words_u32[2 * (m0 + srow)] : words_u32[m0 + srow]);
            const float* src = emb + (size_t)wd * Eq + kc0 * 32 + sseg * 8;
            float4 v0 = *(const float4*)src;
            float4 v1 = *(const float4*)(src + 4);
            _Float16 h8[8] = {(_Float16)v0.x, (_Float16)v0.y, (_Float16)v0.z, (_Float16)v0.w,
                              (_Float16)v1.x, (_Float16)v1.y, (_Float16)v1.z, (_Float16)v1.w};
            *(uint4*)(At + srow * 40 + sseg * 8) = *(const uint4*)h8;
        }
        __syncthreads();
        // B fragments (global, coalesced 1KB/wave) and A fragments (LDS)
        v8hf Bf[4];
        #pragma unroll
        for (int nf = 0; nf < 4; ++nf) {
            size_t fg = (size_t)(ntb + nf) * kcn + kc0;
            Bf[nf] = __builtin_bit_cast(v8hf, *(const uint4*)(PB + (fg * 64 + lane) * 8));
        }
        #pragma unroll
        for (int mf = 0; mf < 4; ++mf) {
            v8hf Af = __builtin_bit_cast(v8hf,
                *(const uint4*)(At + (mf * 16 + (lane & 15)) * 40 + (lane >> 4) * 8));
            #pragma unroll
            for (int nf = 0; nf < 4; ++nf)
                acc[mf][nf] = __builtin_amdgcn_mfma_f32_16x16x32_f16(Af, Bf[nf], acc[mf][nf], 0, 0, 0);
        }
        __syncthreads();
    }
    // epilogue: D col = lane&15, row = (lane>>4)*4 + r  (verified mapping)
    #pragma unroll
    for (int nf = 0; nf < 4; ++nf) {
        int colb = n0w + nf * 16 + (lane & 15);
        float bb = (colb < Nvalid) ? bias[colb] : 0.f;
        #pragma unroll
        for (int mf = 0; mf < 4; ++mf) {
            int rowb = m0 + mf * 16 + (lane >> 4) * 4;
            #pragma unroll
            for (int r = 0; r < 4; ++r) {
                float v = acc[mf][nf][r] + bb;
                if (OUTT == 1) {
                    ((_Float16*)Cptr)[(size_t)(rowb + r) * Nstr + colb] = (_Float16)v;
                } else {
                    if (colb < Nvalid)
                        ((float*)Cptr)[(size_t)(rowb + r) * Nstr + colb] = v;
                }
            }
        }
    }
}

// ---------------- MFMA LSTM (round-18/19 verified), xg f16 full-width, single phase ----------------
__global__ __launch_bounds__(1024)
void lstm_mfma(const _Float16* __restrict__ xg,   // [M][2048] f16, col = dir*1024+g*256+j
               const _Float16* __restrict__ PAf, const _Float16* __restrict__ PAb,
               const unsigned* __restrict__ len_u32,
               const unsigned* __restrict__ dflags,
               _Float16* __restrict__ out)        // [M][512] f16
{
    extern __shared__ char lds_raw[];
    _Float16* ldsA = (_Float16*)lds_raw;                       // 128KB: [128][64][8]
    float*    gbuf = (float*)(lds_raw + 131072);               // [4][1032] f32 = 16512B
    _Float16* h16  = (_Float16*)(lds_raw + 131072 + 16512);    // [2][4][264] = 4224B

    const int tid = threadIdx.x;
    const int bid = blockIdx.x;
    const int dir = bid >> 4;
    const int b0  = (bid & 15) * 4;
    const int w    = tid >> 6;
    const int lane = tid & 63;
    const int n    = lane & 15;
    const int kg   = lane >> 4;
    const int bu   = tid >> 8;
    const int j    = tid & 255;
    const _Float16* __restrict__ PA = dir ? PAb : PAf;
    const bool l64 = (dflags[0] & 2u) != 0u;
    const int mylen = (int)(l64 ? len_u32[2 * (b0 + bu)] : len_u32[b0 + bu]);

    for (int chunk = tid; chunk < 8192; chunk += 1024) {
        int lfrag = chunk >> 6, lane_s = chunk & 63;
        int w_s = lfrag >> 3, kc_s = lfrag & 7;
        int fg = w_s * 32 + 8 + kc_s;
        *(uint4*)(ldsA + (size_t)chunk * 8) = *(const uint4*)(PA + ((size_t)fg * 64 + lane_s) * 8);
    }
    uint4 Ar[4];
    #pragma unroll
    for (int kc = 0; kc < 4; ++kc)
        Ar[kc] = *(const uint4*)(PA + ((size_t)(w * 32 + kc) * 64 + lane) * 8);

    float c = 0.f, hreg = 0.f;
    h16[0 * 1056 + bu * 264 + j] = (_Float16)0.f;
    __syncthreads();

    for (int t = 0; t < Tq; ++t) {
        const int teff = dir ? (Tq - 1 - t) : t;
        const int par = t & 1;
        const _Float16* hrd = h16 + par * 1056;

        const _Float16* xr = xg + ((size_t)(b0 + bu) * Tq + teff) * 2048 + dir * 1024 + j;
        float xv0 = (float)xr[0], xv1 = (float)xr[256], xv2 = (float)xr[512], xv3 = (float)xr[768];

        v4f acc0 = {0.f, 0.f, 0.f, 0.f};
        v4f acc1 = {0.f, 0.f, 0.f, 0.f};
        v4f acc2 = {0.f, 0.f, 0.f, 0.f};
        v4f acc3 = {0.f, 0.f, 0.f, 0.f};
        #pragma unroll
        for (int kc = 0; kc < 8; ++kc) {
            v8hf B;
            if (n < 4) {
                uint4 hb = *(const uint4*)(hrd + n * 264 + kc * 32 + kg * 8);
                B = __builtin_bit_cast(v8hf, hb);
            } else {
                uint4 z = {0u, 0u, 0u, 0u};
                B = __builtin_bit_cast(v8hf, z);
            }
            v8hf A0;
            if (kc < 4) A0 = __builtin_bit_cast(v8hf, Ar[kc]);
            else A0 = __builtin_bit_cast(v8hf, *(const uint4*)(PA + ((size_t)(w * 32 + kc) * 64 + lane) * 8));
            acc0 = __builtin_amdgcn_mfma_f32_16x16x32_f16(A0, B, acc0, 0, 0, 0);
            v8hf A1 = __builtin_bit_cast(v8hf, *(const uint4*)(ldsA + ((size_t)(w * 8 + kc) * 64 + lane) * 8));
            acc1 = __builtin_amdgcn_mfma_f32_16x16x32_f16(A1, B, acc1, 0, 0, 0);
            v8hf A2 = __builtin_bit_cast(v8hf, *(const uint4*)(PA + ((size_t)(w * 32 + 16 + kc) * 64 + lane) * 8));
            acc2 = __builtin_amdgcn_mfma_f32_16x16x32_f16(A2, B, acc2, 0, 0, 0);
            v8hf A3 = __builtin_bit_cast(v8hf, *(const uint4*)(PA + ((size_t)(w * 32 + 24 + kc) * 64 + lane) * 8));
            acc3 = __builtin_amdgcn_mfma_f32_16x16x32_f16(A3, B, acc3, 0, 0, 0);
        }
        if (n < 4) {
            float* gp = gbuf + n * 1032 + w * 64 + kg * 4;
            gp[0]  = acc0[0]; gp[1]  = acc0[1]; gp[2]  = acc0[2]; gp[3]  = acc0[3];
            gp[16] = acc1[0]; gp[17] = acc1[1]; gp[18] = acc1[2]; gp[19] = acc1[3];
            gp[32] = acc2[0]; gp[33] = acc2[1]; gp[34] = acc2[2]; gp[35] = acc2[3];
            gp[48] = acc3[0]; gp[49] = acc3[1]; gp[50] = acc3[2]; gp[51] = acc3[3];
        }
        __syncthreads();
        {
            float g0 = xv0 + gbuf[bu * 1032 + 0 * 256 + j];
            float g1 = xv1 + gbuf[bu * 1032 + 1 * 256 + j];
            float g2 = xv2 + gbuf[bu * 1032 + 2 * 256 + j];
            float g3 = xv3 + gbuf[bu * 1032 + 3 * 256 + j];
            float ig = sigmoidf_(g0), fg = sigmoidf_(g1);
            float gg = tanhf_(g2), og = sigmoidf_(g3);
            float cn = fg * c + ig * gg;
            float hn = og * tanhf_(cn);
            bool m = (teff < mylen);
            float hm = m ? hn : hreg;
            c = m ? cn : c;
            hreg = hm;
            h16[(par ^ 1) * 1056 + bu * 264 + j] = (_Float16)hm;
            size_t orow = (size_t)(b0 + bu) * Tq + teff;
            out[orow * 512 + dir * 256 + j] = (_Float16)hm;
        }
        __syncthreads();
    }
}

extern "C" void kernel_launch(void* const* d_in, const int* in_sizes, int n_in,
                              void* d_out, int out_size, void* d_ws, size_t ws_size,
                              hipStream_t stream)
{
    const unsigned* words  = (const unsigned*)d_in[0];
    const unsigned* lens   = (const unsigned*)d_in[1];
    const float* emb     = (const float*)d_in[2];
    const float* l1f_Wih = (const float*)d_in[3];
    const float* l1f_Whh = (const float*)d_in[4];
    const float* l1f_bih = (const float*)d_in[5];
    const float* l1f_bhh = (const float*)d_in[6];
    const float* l1b_Wih = (const float*)d_in[7];
    const float* l1b_Whh = (const float*)d_in[8];
    const float* l1b_bih = (const float*)d_in[9];
    const float* l1b_bhh = (const float*)d_in[10];
    const float* l2f_Wih = (const float*)d_in[11];
    const float* l2f_Whh = (const float*)d_in[12];
    const float* l2f_bih = (const float*)d_in[13];
    const float* l2f_bhh = (const float*)d_in[14];
    const float* l2b_Wih = (const float*)d_in[15];
    const float* l2b_Whh = (const float*)d_in[16];
    const float* l2b_bih = (const float*)d_in[17];
    const float* l2b_bhh = (const float*)d_in[18];
    const float* cls_W   = (const float*)d_in[19];
    const float* cls_b   = (const float*)d_in[20];
    (void)in_sizes; (void)n_in; (void)out_size; (void)ws_size;

    char* ws = (char*)d_ws;
    size_t off = 0;
    auto alloc = [&](size_t b) { void* p = ws + off; off += (b + 255) & ~(size_t)255; return p; };
    _Float16*  xg = (_Float16*)alloc((size_t)Mq * 2048 * 2);  // 128 MiB, full width (no phasing)
    _Float16*  o1 = (_Float16*)alloc((size_t)Mq * 512 * 2);   // 32 MiB
    _Float16*  o2 = (_Float16*)alloc((size_t)Mq * 512 * 2);   // 32 MiB
    _Float16* PAk = (_Float16*)alloc((size_t)4 * 262144 * 2); // 2 MiB lstm A-frags
    _Float16* PB1 = (_Float16*)alloc((size_t)2 * 131072 * 2); // 512 KB l1 B-frags (K=128, 2 dirs)
    _Float16* PB2 = (_Float16*)alloc((size_t)2 * 524288 * 2); // 2 MiB l2 B-frags (K=512, 2 dirs)
    _Float16* PBc = (_Float16*)alloc((size_t)131072 * 2);     // 256 KB cls B-frags (Npad=256, K=512)
    float* biasbuf = (float*)alloc((size_t)4 * 1024 * 4);
    unsigned* dflags = (unsigned*)alloc(256);
    // total ~197 MiB

    _Float16* PA1f = PAk;
    _Float16* PA1b = PAk + 262144;
    _Float16* PA2f = PAk + 2 * 262144;
    _Float16* PA2b = PAk + 3 * 262144;

    const size_t ldsBytes = 131072 + 16512 + 4224;   // 151808
    hipFuncSetAttribute((const void*)lstm_mfma, hipFuncAttributeMaxDynamicSharedMemorySize, (int)ldsBytes);

    detect_int64<<<1, 256, 0, stream>>>(words, lens, dflags);
    bias_kernel<<<dim3(16), 256, 0, stream>>>(l1f_bih, l1f_bhh, l1b_bih, l1b_bhh,
                                              l2f_bih, l2f_bhh, l2b_bih, l2b_bhh, biasbuf);
    pack_whh_mfma<<<dim3(128), 256, 0, stream>>>(l1f_Whh, PA1f);
    pack_whh_mfma<<<dim3(128), 256, 0, stream>>>(l1b_Whh, PA1b);
    pack_whh_mfma<<<dim3(128), 256, 0, stream>>>(l2f_Whh, PA2f);
    pack_whh_mfma<<<dim3(128), 256, 0, stream>>>(l2b_Whh, PA2b);
    // B-frag packs: l1 (K=128): 64 ntiles * 4 kc * 64 = 16384 chunks per dir
    pack_w_bfrag<<<dim3(64), 256, 0, stream>>>(l1f_Wih, PB1, 1024, 128, 16384);
    pack_w_bfrag<<<dim3(64), 256, 0, stream>>>(l1b_Wih, PB1 + 131072, 1024, 128, 16384);
    // l2 (K=512): 64 * 16 * 64 = 65536 chunks per dir
    pack_w_bfrag<<<dim3(256), 256, 0, stream>>>(l2f_Wih, PB2, 1024, 512, 65536);
    pack_w_bfrag<<<dim3(256), 256, 0, stream>>>(l2b_Wih, PB2 + 524288, 1024, 512, 65536);
    // cls (Npad=256, K=512): 16 * 16 * 64 = 16384 chunks
    pack_w_bfrag<<<dim3(64), 256, 0, stream>>>(cls_W, PBc, NTAGS, 512, 16384);

    // ---- layer 1: xg = gather(emb) @ [Wih_f || Wih_b]^T + bias ----
    gemm_mfma<2, 1><<<dim3(8, Mq / 64), 256, 0, stream>>>(nullptr, words, emb, dflags,
        PB1, biasbuf, xg, 2048, 128, 2048);
    lstm_mfma<<<32, 1024, ldsBytes, stream>>>(xg, PA1f, PA1b, lens, dflags, o1);
    // ---- layer 2 ----
    gemm_mfma<0, 1><<<dim3(8, Mq / 64), 256, 0, stream>>>(o1, nullptr, nullptr, dflags,
        PB2, biasbuf + 2048, xg, 2048, 512, 2048);
    lstm_mfma<<<32, 1024, ldsBytes, stream>>>(xg, PA2f, PA2b, lens, dflags, o2);
    // ---- classifier -> d_out (f32) ----
    gemm_mfma<0, 0><<<dim3(1, Mq / 64), 256, 0, stream>>>(o2, nullptr, nullptr, dflags,
        PBc, cls_b, d_out, NTAGS, 512, NTAGS);
}